// Round 15
// baseline (92.403 us; speedup 1.0000x reference)
//
#include <hip/hip_runtime.h>

// Conv4d implicit GEMM, v15 = ct=8 wave tiles @ 1 wave/SIMD (deep-ILP regime).
// wprep: weights f32 -> bf16 in MFMA-fragment order Wg[off][rt][ks][lane][8].
// sprep: input f32 -> bf16 half-slabs S[(b,w',x')][ks][rem=y'*18+z'][32 ci],
//        granule-swizzled: granule g of row rem at g ^ ((rem>>1)&3).
// main:  block = (b,w,x), 128 thr / 2 waves; wave owns 64co x 128sp (y-tiles 8wv..8wv+7).
//        512 blocks x 2 waves = 1024 waves = 1 wave/SIMD; VGPR budget 512 -> acc[4][8]
//        (128) + af[2][3][4] (96) + bb[2][10] (80) all live, no spill tier.
//        54 phases u (tick p=u/3 over (kwx,ks), q=u%3 over kz). Per phase:
//          q==0: JIT bb read (cross-tick read-ahead would race partner's stage)
//          q==0: STAGE_B(p+1) -> slot (p+1)&1   [11 gll/wave, drained a tick later]
//          LOAD_AF(next phase) global->VGPR ring [12 loads, latency hides under MFMA]
//          q<2 : bb read-ahead (same slab)
//          96 MFMA from current banks (1862 cyc matrix-pipe: the wave alone feeds SIMD)
//          q==2: vmcnt(0)+barrier (free: stages issued ~5600 cyc earlier)
//        Per-phase read-issue ~90 cyc << 1862 MFMA -> single wave saturates the pipe.

typedef __attribute__((ext_vector_type(8))) short bf16x8;
typedef __attribute__((ext_vector_type(4))) float f32x4;
typedef __attribute__((ext_vector_type(8))) unsigned short ushort8;
typedef unsigned short u16;
typedef unsigned int u32;

#define S_OFF_BYTES 663552u          // Wg = 81*4096 u16
#define WS_NEEDED   27537408u        // + 648 slabs * 41472 B

__device__ __forceinline__ u16 f2bf(float f) {
    u32 u = __float_as_uint(f);
    u += 0x7FFFu + ((u >> 16) & 1u);   // RNE
    return (u16)(u >> 16);
}

// ---------------- pre-pass 1: weights ----------------
__global__ __launch_bounds__(256) void wprep(const float* __restrict__ ker, u16* __restrict__ wg) {
    const int g = blockIdx.x * 256 + threadIdx.x;      // 0..41471
    const int l = g & 63, ks = (g >> 6) & 1, rt = (g >> 7) & 3, off = g >> 9;
    const int co  = rt * 16 + (l & 15);
    const int ci0 = ks * 32 + (l >> 4) * 8;
    const float* p = ker + (size_t)off * 4096 + co;
    ushort8 v;
#pragma unroll
    for (int e = 0; e < 8; ++e) v[e] = f2bf(p[(size_t)(ci0 + e) * 64]);
    *(ushort8*)(wg + (size_t)g * 8) = v;
}

// ---------------- pre-pass 2: input half-slabs (granule-swizzled) ----------------
__global__ __launch_bounds__(256) void sprep(const float* __restrict__ in, u16* __restrict__ s) {
    __shared__ u16 L[64 * 330];                        // [ci][rem padded]
    const int blk = blockIdx.x;                        // 648 = 2*18*18
    const int b = blk / 324, wx = blk - b * 324;
    const float* src = in + (size_t)b * 6718464 + (wx / 18) * 5832 + (wx % 18) * 324;
    const int t = threadIdx.x;
    for (int i = t; i < 5184; i += 256) {              // 64 ci * 81 float4
        const int ci = i / 81, j = i - ci * 81;
        float4 v = *(const float4*)(src + (size_t)ci * 104976 + j * 4);
        u32* q = (u32*)&L[ci * 330 + j * 4];
        q[0] = f2bf(v.x) | ((u32)f2bf(v.y) << 16);
        q[1] = f2bf(v.z) | ((u32)f2bf(v.w) << 16);
    }
    __syncthreads();
    u16* dst = s + (size_t)blk * 20736;                // [ks][rem][32 swizzled]
    for (int i = t; i < 2592; i += 256) {              // 2 ks * 324 rem * 4 granules
        const int ks = i / 1296, r4 = i - ks * 1296;
        const int rem = r4 >> 2, g = r4 & 3;
        ushort8 v;
#pragma unroll
        for (int e = 0; e < 8; ++e) v[e] = L[(ks * 32 + g * 8 + e) * 330 + rem];
        const int gp = g ^ ((rem >> 1) & 3);           // involution granule swizzle
        *(ushort8*)(dst + ks * 10368 + rem * 32 + gp * 8) = v;
    }
}

// ---------------- main ----------------
__global__ __launch_bounds__(128, 1)
void conv4d_main(const u16* __restrict__ wg, const u16* __restrict__ s, float* __restrict__ out) {
    __shared__ u16 Bs[2][10368];                       // 2-slot B half-slab ring (tick&1)

    // bijective XCD swizzle (512 % 8 == 0)
    const int bid = blockIdx.x;
    const int bs  = (bid & 7) * 64 + (bid >> 3);
    const int b   = bs >> 8;
    const int w   = (bs >> 4) & 15;
    const int x   = bs & 15;

    const int t  = threadIdx.x, wv = t >> 6, l = t & 63;
    const int lg = l >> 4, ll = l & 15;

    f32x4 acc[4][8];
#pragma unroll
    for (int i = 0; i < 4; ++i)
#pragma unroll
        for (int j = 0; j < 8; ++j) acc[i][j] = (f32x4){0.f, 0.f, 0.f, 0.f};

    const u16* sb = s + (size_t)(b * 324 + w * 18 + x) * 20736;

    bf16x8 af[2][3][4];                                // phase-banked A frags (96 VGPR)
    bf16x8 bb[2][10];                                  // phase-banked B rows  (80 VGPR)

    // B half-slab for tick h -> Bs[h&1]: 11 gll/wave (10 full + l<8 masked)
#define STAGE_B(h)                                                                       \
    do {                                                                                 \
        const int kwx_ = (h) >> 1, ks_ = (h) & 1;                                        \
        const int kw_ = kwx_ / 3, kx_ = kwx_ - kw_ * 3;                                  \
        const u16* src_ = sb + (size_t)(kw_ * 18 + kx_) * 20736 + ks_ * 10368;           \
        const int base_ = wv * 648;                                                      \
        _Pragma("unroll")                                                                \
        for (int k_ = 0; k_ < 10; ++k_) {                                                \
            const int i_ = base_ + k_ * 64 + l;                                          \
            __builtin_amdgcn_global_load_lds(                                            \
                (const __attribute__((address_space(1))) u32*)(src_ + (size_t)i_ * 8),   \
                (__attribute__((address_space(3))) u32*)&Bs[(h) & 1][i_ * 8], 16, 0, 0); \
        }                                                                                \
        if (l < 8) {                                                                     \
            const int i_ = base_ + 640 + l;                                              \
            __builtin_amdgcn_global_load_lds(                                            \
                (const __attribute__((address_space(1))) u32*)(src_ + (size_t)i_ * 8),   \
                (__attribute__((address_space(3))) u32*)&Bs[(h) & 1][i_ * 8], 16, 0, 0); \
        }                                                                                \
    } while (0)

    // A fragments for phase U into bank BK: 12 x global dwordx4 (L2-resident)
#define LOAD_AF(BK, U)                                                                   \
    do {                                                                                 \
        const int tk_ = (U) / 3, kz_ = (U) % 3;                                          \
        const int kwx_ = tk_ >> 1, ks_ = tk_ & 1;                                        \
        _Pragma("unroll")                                                                \
        for (int ky_ = 0; ky_ < 3; ++ky_)                                                \
            _Pragma("unroll")                                                            \
            for (int rt_ = 0; rt_ < 4; ++rt_)                                            \
                af[BK][ky_][rt_] = *(const bf16x8*)(wg                                   \
                    + (size_t)(kwx_ * 9 + ky_ * 3 + kz_) * 4096                          \
                    + (size_t)(rt_ * 2 + ks_) * 512 + l * 8);                            \
    } while (0)

    // B rows (10) for phase (tick P, kz KZ) into bank BK
#define READ_BB(BK, P, KZ)                                                               \
    do {                                                                                 \
        const u16* Tb_ = Bs[(P) & 1];                                                    \
        _Pragma("unroll")                                                                \
        for (int j_ = 0; j_ < 10; ++j_) {                                                \
            const int rem_ = (8 * wv + j_) * 18 + ll + (KZ);                             \
            bb[BK][j_] = *(const bf16x8*)&Tb_[rem_ * 32 + ((lg ^ ((rem_ >> 1) & 3)) << 3)]; \
        }                                                                                \
    } while (0)

#define MFMA96(BK)                                                                       \
    do {                                                                                 \
        __builtin_amdgcn_s_setprio(1);                                                   \
        _Pragma("unroll")                                                                \
        for (int ky_ = 0; ky_ < 3; ++ky_)                                                \
            _Pragma("unroll")                                                            \
            for (int ct_ = 0; ct_ < 8; ++ct_)                                            \
                _Pragma("unroll")                                                        \
                for (int rt_ = 0; rt_ < 4; ++rt_)                                        \
                    acc[rt_][ct_] = __builtin_amdgcn_mfma_f32_16x16x32_bf16(             \
                        af[BK][ky_][rt_], bb[BK][ct_ + ky_], acc[rt_][ct_], 0, 0, 0);    \
        __builtin_amdgcn_s_setprio(0);                                                   \
    } while (0)

    // prologue: B(0) staged, A(phase 0) loaded, drain, barrier
    STAGE_B(0);
    LOAD_AF(0, 0);
    asm volatile("s_waitcnt vmcnt(0)" ::: "memory");
    __builtin_amdgcn_sched_barrier(0);
    __builtin_amdgcn_s_barrier();

    for (int u6 = 0; u6 < 54; u6 += 6) {
#pragma unroll
        for (int m = 0; m < 6; ++m) {
            const int u = u6 + m;
            const int p = u / 3;                       // tick (runtime ok: addresses only)
            const int q = m % 3;                       // kz (static)
            const int cur = m & 1, nxt = cur ^ 1;      // banks (static)
            if (q == 0) READ_BB(cur, p, 0);            // JIT after tick barrier
            if (q == 0 && p + 1 < 18) STAGE_B(p + 1);  // drained at tick end (~5600cyc)
            if (u + 1 < 54) LOAD_AF(nxt, u + 1);       // ring: latency hides under MFMA
            if (q < 2) READ_BB(nxt, p, q + 1);         // same slab: race-free read-ahead
            MFMA96(cur);
            if (q == 2 && u < 53) {
                asm volatile("s_waitcnt vmcnt(0)" ::: "memory");  // stages long retired
                __builtin_amdgcn_sched_barrier(0);
                __builtin_amdgcn_s_barrier();
            }
        }
    }
#undef STAGE_B
#undef LOAD_AF
#undef READ_BB
#undef MFMA96

    float* ob = out + (size_t)b * 4194304 + (size_t)w * 4096 + (size_t)x * 256;
#pragma unroll
    for (int rt = 0; rt < 4; ++rt) {
        const int co0 = rt * 16 + 4 * lg;
#pragma unroll
        for (int ct = 0; ct < 8; ++ct) {
            const int base = (8 * wv + ct) * 16 + ll;
#pragma unroll
            for (int r = 0; r < 4; ++r)
                ob[(size_t)(co0 + r) * 65536 + base] = acc[rt][ct][r];
        }
    }
}

// ---------------- fallback (round-1 kernel, used if ws too small) ----------------
__global__ __launch_bounds__(512, 2)
void conv4d_mfma(const float* __restrict__ in, const float* __restrict__ ker,
                 float* __restrict__ out) {
    __shared__ unsigned short T[18 * 18 * 64];
    __shared__ unsigned short Wt[2][64 * 64];
    const int bx = blockIdx.x;
    const int b = bx >> 8, wsp = (bx >> 4) & 15, x = bx & 15;
    const int t = threadIdx.x, wv = t >> 6, l = t & 63;
    const int lg = l >> 4, ll = l & 15;
    const float* inb = in + (size_t)b * 6718464 + wsp * 5832 + x * 324;
    f32x4 acc[4][2];
#pragma unroll
    for (int i = 0; i < 4; ++i)
#pragma unroll
        for (int j = 0; j < 2; ++j) acc[i][j] = (f32x4){0.f, 0.f, 0.f, 0.f};
#pragma unroll
    for (int f0 = 0; f0 < 4096; f0 += 512) {
        const int f = f0 + t, ci = f >> 6, co = f & 63;
        Wt[0][co * 64 + ((((ci >> 3) ^ (co & 7)) << 3) | (ci & 7))] = f2bf(ker[f]);
    }
    for (int off = 0; off < 81; ++off) {
        const int sub = off % 9;
        if (sub == 0) {
            const int kw = off / 27, kx = (off / 9) % 3;
            const float* p = inb + kw * 5832 + kx * 324;
            for (int f = t; f < 18 * 18 * 64; f += 512) {
                const int ci = f / 324, rem = f - ci * 324, zp = rem % 18;
                T[rem * 64 + ((((ci >> 3) ^ (zp & 7)) << 3) | (ci & 7))] =
                    f2bf(p[(size_t)ci * 104976 + rem]);
            }
        }
        if (off + 1 < 81) {
            const float* p = ker + (off + 1) * 4096;
            unsigned short* wb = Wt[(off + 1) & 1];
#pragma unroll
            for (int f0 = 0; f0 < 4096; f0 += 512) {
                const int f = f0 + t, ci = f >> 6, co = f & 63;
                wb[co * 64 + ((((ci >> 3) ^ (co & 7)) << 3) | (ci & 7))] = f2bf(p[f]);
            }
        }
        if (sub == 0) __syncthreads();
        const int ky = sub / 3, kz = sub - ky * 3;
        const int zp = ll + kz, zs = zp & 7;
#pragma unroll
        for (int ks = 0; ks < 2; ++ks) {
            bf16x8 af[4];
#pragma unroll
            for (int rt = 0; rt < 4; ++rt)
                af[rt] = *(const bf16x8*)&Wt[off & 1][(rt * 16 + ll) * 64 + (((lg + 4 * ks) ^ (ll & 7)) << 3)];
#pragma unroll
            for (int ct = 0; ct < 2; ++ct) {
                const int rem = (2 * wv + ct + ky) * 18 + zp;
                const bf16x8 bfr = *(const bf16x8*)&T[rem * 64 + (((lg + 4 * ks) ^ zs) << 3)];
#pragma unroll
                for (int rt = 0; rt < 4; ++rt)
                    acc[rt][ct] = __builtin_amdgcn_mfma_f32_16x16x32_bf16(af[rt], bfr, acc[rt][ct], 0, 0, 0);
            }
        }
        __syncthreads();
    }
    float* ob = out + (size_t)b * 4194304 + wsp * 4096 + x * 256;
#pragma unroll
    for (int rt = 0; rt < 4; ++rt) {
        const int co0 = rt * 16 + 4 * lg;
#pragma unroll
        for (int ct = 0; ct < 2; ++ct) {
            const int base = (2 * wv + ct) * 16 + ll;
#pragma unroll
            for (int r = 0; r < 4; ++r)
                ob[(size_t)(co0 + r) * 65536 + base] = acc[rt][ct][r];
        }
    }
}

extern "C" void kernel_launch(void* const* d_in, const int* in_sizes, int n_in,
                              void* d_out, int out_size, void* d_ws, size_t ws_size,
                              hipStream_t stream) {
    const float* in  = (const float*)d_in[0];
    const float* ker = (const float*)d_in[1];
    float* out = (float*)d_out;
    if (ws_size >= (size_t)WS_NEEDED) {
        u16* wg = (u16*)d_ws;
        u16* s  = (u16*)((char*)d_ws + S_OFF_BYTES);
        wprep<<<dim3(162), dim3(256), 0, stream>>>(ker, wg);
        sprep<<<dim3(648), dim3(256), 0, stream>>>(in, s);
        conv4d_main<<<dim3(512), dim3(128), 0, stream>>>(wg, s, out);
    } else {
        conv4d_mfma<<<dim3(512), dim3(512), 0, stream>>>(in, ker, out);
    }
}

// Round 16
// 85.392 us; speedup vs baseline: 1.0821x; 1.0821x over previous
//
#include <hip/hip_runtime.h>

// Conv4d implicit GEMM, v16 = v14 schedule + 2co x 2sp wave split + fused prep.
// prep (single kernel, 810 blocks): blocks 0..647 = sprep (input f32 -> bf16 half-slabs
//   S[(b,w',x')][ks][rem][32 ci], granule g of row rem stored at g^((rem>>1)&3));
//   blocks 648..809 = wprep (weights -> Wg[off][rt][ks][lane][8] fragment order).
// main:  block = (b,w,x), 256 thr / 4 waves. Wave = (co-half ch = wv>>1, sp-half sh = wv&1):
//        tile 32co x 128sp (rt 0..1 at co 32ch, ct 0..7 at y 8sh..8sh+7).
//        A-reads/phase: 6 (was 12); B-rows: 10 shared across 8ct x 3ky (was 6 x 2 banks).
//        LDS reads per CU per phase 144 -> 128. Schedule = v14 verbatim:
//        54 phases; A 3-slot ring staged 2 phases ahead (JIT ky0 read, ky1/ky2 shadowed);
//        B 2-slot ring staged at q0 for tick p+1, rows read one phase ahead;
//        counted WAITBAR(9/3/3) per phase (stages span phases, never drained mid-loop).

typedef __attribute__((ext_vector_type(8))) short bf16x8;
typedef __attribute__((ext_vector_type(4))) float f32x4;
typedef __attribute__((ext_vector_type(8))) unsigned short ushort8;
typedef unsigned short u16;
typedef unsigned int u32;

#define S_OFF_BYTES 663552u          // Wg = 81*4096 u16
#define WS_NEEDED   27537408u        // + 648 slabs * 41472 B

__device__ __forceinline__ u16 f2bf(float f) {
    u32 u = __float_as_uint(f);
    u += 0x7FFFu + ((u >> 16) & 1u);   // RNE
    return (u16)(u >> 16);
}

// ---------------- fused pre-pass: sprep (blocks 0..647) + wprep (648..809) ----------------
__global__ __launch_bounds__(256) void prep(const float* __restrict__ in,
                                            const float* __restrict__ ker,
                                            u16* __restrict__ s, u16* __restrict__ wg) {
    const int blk = blockIdx.x;
    const int t = threadIdx.x;
    if (blk >= 648) {                                  // ---- wprep ----
        const int g = (blk - 648) * 256 + t;           // 0..41471
        const int l = g & 63, ks = (g >> 6) & 1, rt = (g >> 7) & 3, off = g >> 9;
        const int co  = rt * 16 + (l & 15);
        const int ci0 = ks * 32 + (l >> 4) * 8;
        const float* p = ker + (size_t)off * 4096 + co;
        ushort8 v;
#pragma unroll
        for (int e = 0; e < 8; ++e) v[e] = f2bf(p[(size_t)(ci0 + e) * 64]);
        *(ushort8*)(wg + (size_t)g * 8) = v;
        return;
    }
    // ---- sprep ----
    __shared__ u16 L[64 * 330];                        // [ci][rem padded]
    const int b = blk / 324, wx = blk - b * 324;
    const float* src = in + (size_t)b * 6718464 + (wx / 18) * 5832 + (wx % 18) * 324;
    for (int i = t; i < 5184; i += 256) {              // 64 ci * 81 float4
        const int ci = i / 81, j = i - ci * 81;
        float4 v = *(const float4*)(src + (size_t)ci * 104976 + j * 4);
        u32* q = (u32*)&L[ci * 330 + j * 4];
        q[0] = f2bf(v.x) | ((u32)f2bf(v.y) << 16);
        q[1] = f2bf(v.z) | ((u32)f2bf(v.w) << 16);
    }
    __syncthreads();
    u16* dst = s + (size_t)blk * 20736;                // [ks][rem][32 swizzled]
    for (int i = t; i < 2592; i += 256) {              // 2 ks * 324 rem * 4 granules
        const int ks = i / 1296, r4 = i - ks * 1296;
        const int rem = r4 >> 2, g = r4 & 3;
        ushort8 v;
#pragma unroll
        for (int e = 0; e < 8; ++e) v[e] = L[(ks * 32 + g * 8 + e) * 330 + rem];
        const int gp = g ^ ((rem >> 1) & 3);           // involution granule swizzle
        *(ushort8*)(dst + ks * 10368 + rem * 32 + gp * 8) = v;
    }
}

// ---------------- main ----------------
__global__ __launch_bounds__(256, 1)
void conv4d_main(const u16* __restrict__ wg, const u16* __restrict__ s, float* __restrict__ out) {
    __shared__ u16 A[3][6144];                         // 3 x 12288B A-chunk ring (slot = phase%3)
    __shared__ u16 Bq[2][10368];                       // 2 x 20736B B half-slab ring (tick&1)

    // bijective XCD swizzle (512 % 8 == 0)
    const int bid = blockIdx.x;
    const int bs  = (bid & 7) * 64 + (bid >> 3);
    const int b   = bs >> 8;
    const int w   = (bs >> 4) & 15;
    const int x   = bs & 15;

    const int t  = threadIdx.x, wv = t >> 6, l = t & 63;
    const int lg = l >> 4, ll = l & 15;
    const int ch = wv >> 1;            // co-half: rt frags {2ch, 2ch+1}
    const int sh = wv & 1;             // sp-half: y rows 8sh..8sh+7

    f32x4 acc[2][8];
#pragma unroll
    for (int i = 0; i < 2; ++i)
#pragma unroll
        for (int j = 0; j < 8; ++j) acc[i][j] = (f32x4){0.f, 0.f, 0.f, 0.f};

    const u16* sb = s + (size_t)(b * 324 + w * 18 + x) * 20736;

    bf16x8 af[2][2];                                   // within-phase A ping-pong (2 rt)
    bf16x8 bb[2][10];                                  // phase-banked B rows

#define STAGE_A(tk, KZ)                                                                  \
    do {                                                                                 \
        const int kwx_ = (tk) >> 1, ks2_ = (tk) & 1;                                     \
        _Pragma("unroll")                                                                \
        for (int c_ = 0; c_ < 3; ++c_) {                                                 \
            const u16* src_ = wg + (size_t)(kwx_ * 9 + c_ * 3 + (KZ)) * 4096             \
                              + wv * 1024 + ks2_ * 512 + l * 8;                          \
            __builtin_amdgcn_global_load_lds(                                            \
                (const __attribute__((address_space(1))) u32*)src_,                      \
                (__attribute__((address_space(3))) u32*)&A[KZ][c_ * 2048 + wv * 512 + l * 8], \
                16, 0, 0);                                                               \
        }                                                                                \
    } while (0)

#define STAGE_B(h)                                                                       \
    do {                                                                                 \
        const int kwx_ = (h) >> 1, ks_ = (h) & 1;                                        \
        const int kw_ = kwx_ / 3, kx_ = kwx_ - kw_ * 3;                                  \
        const u16* src_ = sb + (size_t)(kw_ * 18 + kx_) * 20736 + ks_ * 10368;           \
        const int base_ = wv * 324;                                                      \
        _Pragma("unroll")                                                                \
        for (int k_ = 0; k_ < 5; ++k_) {                                                 \
            const int i_ = base_ + k_ * 64 + l;                                          \
            __builtin_amdgcn_global_load_lds(                                            \
                (const __attribute__((address_space(1))) u32*)(src_ + (size_t)i_ * 8),   \
                (__attribute__((address_space(3))) u32*)&Bq[(h) & 1][i_ * 8], 16, 0, 0); \
        }                                                                                \
        if (l < 4) {                                                                     \
            const int i_ = base_ + 320 + l;                                              \
            __builtin_amdgcn_global_load_lds(                                            \
                (const __attribute__((address_space(1))) u32*)(src_ + (size_t)i_ * 8),   \
                (__attribute__((address_space(3))) u32*)&Bq[(h) & 1][i_ * 8], 16, 0, 0); \
        }                                                                                \
    } while (0)

    // A fragments (2 rt of this wave's co-half) for slot SLOT, ky KY -> bank BK
#define READ_A(BK, SLOT, KY)                                                             \
    do {                                                                                 \
        _Pragma("unroll")                                                                \
        for (int rt_ = 0; rt_ < 2; ++rt_)                                                \
            af[BK][rt_] = *(const bf16x8*)&A[SLOT][(KY) * 2048 + (2 * ch + rt_) * 512 + l * 8]; \
    } while (0)

    // B rows (10, y = 8sh..8sh+9) for (tick parity TKPAR, kz QQ) -> bank BK
#define READ_B(BK, TKPAR, QQ)                                                            \
    do {                                                                                 \
        const u16* Tb_ = Bq[TKPAR];                                                      \
        _Pragma("unroll")                                                                \
        for (int j_ = 0; j_ < 10; ++j_) {                                                \
            const int rem_ = (8 * sh + j_) * 18 + ll + (QQ);                             \
            bb[BK][j_] = *(const bf16x8*)&Tb_[rem_ * 32 + ((lg ^ ((rem_ >> 1) & 3)) << 3)]; \
        }                                                                                \
    } while (0)

#define MFMA16(ABK, BBK, KY)                                                             \
    do {                                                                                 \
        __builtin_amdgcn_s_setprio(1);                                                   \
        _Pragma("unroll")                                                                \
        for (int ct_ = 0; ct_ < 8; ++ct_)                                                \
            _Pragma("unroll")                                                            \
            for (int rt_ = 0; rt_ < 2; ++rt_)                                            \
                acc[rt_][ct_] = __builtin_amdgcn_mfma_f32_16x16x32_bf16(                 \
                    af[ABK][rt_], bb[BBK][ct_ + (KY)], acc[rt_][ct_], 0, 0, 0);          \
        __builtin_amdgcn_s_setprio(0);                                                   \
    } while (0)

#define WAITBAR(N)                                                                       \
    do {                                                                                 \
        asm volatile("s_waitcnt vmcnt(" #N ")" ::: "memory");                            \
        __builtin_amdgcn_sched_barrier(0);                                               \
        __builtin_amdgcn_s_barrier();                                                    \
    } while (0)

    // prologue: A slots for phases 0,1; B(0); full drain; bank B(phase 0)
    STAGE_A(0, 0);
    STAGE_A(0, 1);
    STAGE_B(0);
    WAITBAR(0);
    READ_B(0, 0, 0);

    for (int u6 = 0; u6 < 54; u6 += 6) {
#pragma unroll
        for (int m = 0; m < 6; ++m) {
            const int u = u6 + m;
            const int cb = m & 1;                      // B bank of this phase (static)
            if (u < 52) STAGE_A((u + 2) / 3, (m + 2) % 3);
            if (m % 3 == 0 && u < 51) STAGE_B(u / 3 + 1);
            READ_A(0, m % 3, 0);                       // ky0 JIT (slot staged u-2: safe)
            if (u < 53) READ_B(cb ^ 1, (((m + 1) / 3) & 1), (m + 1) % 3);
            READ_A(1, m % 3, 1);                       // ky1 ahead, flies under ky0 MFMA
            __builtin_amdgcn_sched_barrier(0);
            MFMA16(0, cb, 0);                          // waits only ky0 frags (oldest)
            READ_A(0, m % 3, 2);                       // ky2 ahead (bank0 free again)
            __builtin_amdgcn_sched_barrier(0);
            MFMA16(1, cb, 1);
            __builtin_amdgcn_sched_barrier(0);
            MFMA16(0, cb, 2);
            if (u < 53) {
                if (m % 3 == 0) { if (u < 51) WAITBAR(9); else WAITBAR(3); }
                else            { if (u < 52) WAITBAR(3); else WAITBAR(0); }
            }
        }
    }
#undef STAGE_A
#undef STAGE_B
#undef READ_A
#undef READ_B
#undef MFMA16
#undef WAITBAR

    float* ob = out + (size_t)b * 4194304 + (size_t)w * 4096 + (size_t)x * 256;
#pragma unroll
    for (int rt = 0; rt < 2; ++rt) {
        const int co0 = ch * 32 + rt * 16 + 4 * lg;
#pragma unroll
        for (int ct = 0; ct < 8; ++ct) {
            const int base = (8 * sh + ct) * 16 + ll;
#pragma unroll
            for (int r = 0; r < 4; ++r)
                ob[(size_t)(co0 + r) * 65536 + base] = acc[rt][ct][r];
        }
    }
}

// ---------------- fallback (round-1 kernel, used if ws too small) ----------------
__global__ __launch_bounds__(512, 2)
void conv4d_mfma(const float* __restrict__ in, const float* __restrict__ ker,
                 float* __restrict__ out) {
    __shared__ unsigned short T[18 * 18 * 64];
    __shared__ unsigned short Wt[2][64 * 64];
    const int bx = blockIdx.x;
    const int b = bx >> 8, wsp = (bx >> 4) & 15, x = bx & 15;
    const int t = threadIdx.x, wv = t >> 6, l = t & 63;
    const int lg = l >> 4, ll = l & 15;
    const float* inb = in + (size_t)b * 6718464 + wsp * 5832 + x * 324;
    f32x4 acc[4][2];
#pragma unroll
    for (int i = 0; i < 4; ++i)
#pragma unroll
        for (int j = 0; j < 2; ++j) acc[i][j] = (f32x4){0.f, 0.f, 0.f, 0.f};
#pragma unroll
    for (int f0 = 0; f0 < 4096; f0 += 512) {
        const int f = f0 + t, ci = f >> 6, co = f & 63;
        Wt[0][co * 64 + ((((ci >> 3) ^ (co & 7)) << 3) | (ci & 7))] = f2bf(ker[f]);
    }
    for (int off = 0; off < 81; ++off) {
        const int sub = off % 9;
        if (sub == 0) {
            const int kw = off / 27, kx = (off / 9) % 3;
            const float* p = inb + kw * 5832 + kx * 324;
            for (int f = t; f < 18 * 18 * 64; f += 512) {
                const int ci = f / 324, rem = f - ci * 324, zp = rem % 18;
                T[rem * 64 + ((((ci >> 3) ^ (zp & 7)) << 3) | (ci & 7))] =
                    f2bf(p[(size_t)ci * 104976 + rem]);
            }
        }
        if (off + 1 < 81) {
            const float* p = ker + (off + 1) * 4096;
            unsigned short* wb = Wt[(off + 1) & 1];
#pragma unroll
            for (int f0 = 0; f0 < 4096; f0 += 512) {
                const int f = f0 + t, ci = f >> 6, co = f & 63;
                wb[co * 64 + ((((ci >> 3) ^ (co & 7)) << 3) | (ci & 7))] = f2bf(p[f]);
            }
        }
        if (sub == 0) __syncthreads();
        const int ky = sub / 3, kz = sub - ky * 3;
        const int zp = ll + kz, zs = zp & 7;
#pragma unroll
        for (int ks = 0; ks < 2; ++ks) {
            bf16x8 af[4];
#pragma unroll
            for (int rt = 0; rt < 4; ++rt)
                af[rt] = *(const bf16x8*)&Wt[off & 1][(rt * 16 + ll) * 64 + (((lg + 4 * ks) ^ (ll & 7)) << 3)];
#pragma unroll
            for (int ct = 0; ct < 2; ++ct) {
                const int rem = (2 * wv + ct + ky) * 18 + zp;
                const bf16x8 bfr = *(const bf16x8*)&T[rem * 64 + (((lg + 4 * ks) ^ zs) << 3)];
#pragma unroll
                for (int rt = 0; rt < 4; ++rt)
                    acc[rt][ct] = __builtin_amdgcn_mfma_f32_16x16x32_bf16(af[rt], bfr, acc[rt][ct], 0, 0, 0);
            }
        }
        __syncthreads();
    }
    float* ob = out + (size_t)b * 4194304 + wsp * 4096 + x * 256;
#pragma unroll
    for (int rt = 0; rt < 4; ++rt) {
        const int co0 = rt * 16 + 4 * lg;
#pragma unroll
        for (int ct = 0; ct < 2; ++ct) {
            const int base = (2 * wv + ct) * 16 + ll;
#pragma unroll
            for (int r = 0; r < 4; ++r)
                ob[(size_t)(co0 + r) * 65536 + base] = acc[rt][ct][r];
        }
    }
}

extern "C" void kernel_launch(void* const* d_in, const int* in_sizes, int n_in,
                              void* d_out, int out_size, void* d_ws, size_t ws_size,
                              hipStream_t stream) {
    const float* in  = (const float*)d_in[0];
    const float* ker = (const float*)d_in[1];
    float* out = (float*)d_out;
    if (ws_size >= (size_t)WS_NEEDED) {
        u16* wg = (u16*)d_ws;
        u16* s  = (u16*)((char*)d_ws + S_OFF_BYTES);
        prep<<<dim3(810), dim3(256), 0, stream>>>(in, ker, s, wg);
        conv4d_main<<<dim3(512), dim3(256), 0, stream>>>(wg, s, out);
    } else {
        conv4d_mfma<<<dim3(512), dim3(512), 0, stream>>>(in, ker, out);
    }
}